// Round 7
// baseline (905.459 us; speedup 1.0000x reference)
//
#include <hip/hip_runtime.h>

// LiquidODECell: B=4096, D_IN=1024, H=2048, TAU_MIN=0.2, 3 RK2 steps.
// f16 MFMA GEMMs (fp32 accum), fused LDS-transposed epilogues.
// gemmT: 256x256 2-phase deep pipeline using mfma_f32_32x32x16_f16 (EP0/EP1).
// gemmC: 256x128 single-phase deep pipeline, 16x16x32 (EP2 tau+RK2).
// prep_all: one fused grid-strided conversion/pack kernel.

typedef _Float16 f16;
typedef __attribute__((ext_vector_type(4))) _Float16 f16x4;
typedef __attribute__((ext_vector_type(8))) _Float16 f16x8;
typedef __attribute__((ext_vector_type(4))) float f32x4;
typedef __attribute__((ext_vector_type(16))) float f32x16;

#define TAU_MIN_F 0.2f

__device__ __forceinline__ float rcp_fast(float x) { return __builtin_amdgcn_rcpf(x); }
__device__ __forceinline__ float tanh_fast(float u) {
  float t = __expf(2.0f * u);
  return 1.0f - 2.0f * rcp_fast(t + 1.0f);
}
__device__ __forceinline__ float silu_fast(float u) {
  return u * rcp_fast(1.0f + __expf(-u));
}
__device__ __forceinline__ float softplus_fast(float u) {
  return fmaxf(u, 0.0f) + __logf(1.0f + __expf(-fabsf(u)));
}

__device__ __forceinline__ void glds16(const void* g, void* l) {
  __builtin_amdgcn_global_load_lds(
      (const __attribute__((address_space(1))) unsigned int*)g,
      (__attribute__((address_space(3))) unsigned int*)l,
      16, 0, 0);
}

// ---------------- fused prep kernel ----------------
__device__ __forceinline__ void cvt_one(const float* __restrict__ s,
                                        f16* __restrict__ d, int i) {
  float4 v = reinterpret_cast<const float4*>(s)[i];
  f16x4 o = {(_Float16)v.x, (_Float16)v.y, (_Float16)v.z, (_Float16)v.w};
  reinterpret_cast<f16x4*>(d)[i] = o;
}

__global__ __launch_bounds__(256)
void prep_all(const float* __restrict__ x, const float* __restrict__ h,
              const float* __restrict__ Wih, const float* __restrict__ Whh,
              const float* __restrict__ Wt1, const float* __restrict__ Wt2,
              const float* __restrict__ bih, const float* __restrict__ bhh,
              const float* __restrict__ bt1,
              f16* __restrict__ xb, f16* __restrict__ hb,
              f16* __restrict__ Wpre, f16* __restrict__ Wab,
              f16* __restrict__ Wt2b, float* __restrict__ biasp) {
  const int E0 = 1048576;            // x -> xb
  const int E1 = E0 + 524288;        // Wih -> Wpre[0:2048]
  const int E2 = E1 + 1048576;       // Whh -> Wab[0:2048]
  const int E3 = E2 + 1048576;       // Wt2 -> Wt2b
  const int E4 = E3 + 2097152;       // h -> hb
  const int E5 = E4 + 1572864;       // Wt1 split
  const int E6 = E5 + 1024;          // biasp
  const int stride = gridDim.x * 256;
  for (int i = blockIdx.x * 256 + threadIdx.x; i < E6; i += stride) {
    if (i < E0) {
      cvt_one(x, xb, i);
    } else if (i < E1) {
      cvt_one(Wih, Wpre, i - E0);
    } else if (i < E2) {
      cvt_one(Whh, Wab, i - E1);
    } else if (i < E3) {
      cvt_one(Wt2, Wt2b, i - E2);
    } else if (i < E4) {
      cvt_one(h, hb, i - E3);
    } else if (i < E5) {
      int j = i - E4;
      int r = j / 768;
      int c4 = (j - r * 768) * 4;
      float4 v = reinterpret_cast<const float4*>(Wt1)[j];
      f16x4 o = {(_Float16)v.x, (_Float16)v.y, (_Float16)v.z, (_Float16)v.w};
      if (c4 < 1024)
        *reinterpret_cast<f16x4*>(Wpre + (size_t)(2048 + r) * 1024 + c4) = o;
      else
        *reinterpret_cast<f16x4*>(Wab + (size_t)(2048 + r) * 2048 + (c4 - 1024)) = o;
    } else {
      int k = (i - E5) * 4;
      float4 o;
      if (k < 2048) {
        float4 a = *reinterpret_cast<const float4*>(bih + k);
        float4 bv = *reinterpret_cast<const float4*>(bhh + k);
        o = {a.x + bv.x, a.y + bv.y, a.z + bv.z, a.w + bv.w};
      } else {
        o = *reinterpret_cast<const float4*>(bt1 + (k - 2048));
      }
      *reinterpret_cast<float4*>(biasp + k) = o;
    }
  }
}

struct EpArgs {
  const float* biasf;   // EP0: bias_pre[N]
  const f16* pre16;     // EP1: pre [M,4096] f16
  const f16* h16;       // EP1: h this dynamics is evaluated at (f16)
  f16* out_d;           // EP1: diff f16
  f16* out_h;           // EP0: pre16 out; EP1: t1 f16; EP2: h' f16
  const float* bt2;     // EP2
  const f16* diff;      // EP2
  const f16* hb16;      // EP2: RK2 base h (f16)
  float* out_f;         // EP2: fp32 h' out (nullable; final step only)
  float coef;           // EP2 (0.5*dt or dt)
};

// ================= 256x256 2-phase deep-pipeline GEMM, 32x32x16 MFMA =================
// 8 waves (2M x 4N), per-wave 128x64 = 4 x 2 tiles of 32x32.
template <int EP>
__global__ __launch_bounds__(512, 2)
void gemmT(const f16* __restrict__ A, const f16* __restrict__ Bw,
           int N, int K, EpArgs ep) {
  constexpr int BUFB = 32768;
  __shared__ __align__(16) char SH[BUFB * 3];  // 96 KB

  const int gx = gridDim.x;
  const int nwg = gx * gridDim.y;
  const int orig = blockIdx.y * gx + blockIdx.x;
  const int cpx = nwg >> 3;
  const int w = (orig & 7) * cpx + (orig >> 3);
  const int bm = (w % gx) * 256;
  const int bn = (w / gx) * 256;

  const int tid = threadIdx.x;
  const int lane = tid & 63;
  const int wid = tid >> 6;
  const int wr = wid >> 2;  // 0..1
  const int wc = wid & 3;   // 0..3

  // ---- staging: instr j covers 128 rows; 64B rows; chunk-XOR pre-swizzled src ----
  const int srow = wid * 16 + (lane >> 2);                 // 0..127
  const int skof = ((lane & 3) ^ ((lane >> 2) & 3)) << 4;
  const char* Ag0 = (const char*)A + (size_t)(bm + srow) * K * 2 + skof;
  const char* Ag1 = Ag0 + (size_t)128 * K * 2;
  const char* Bg0 = (const char*)Bw + (size_t)(bn + srow) * K * 2 + skof;
  const char* Bg1 = Bg0 + (size_t)128 * K * 2;
  const int dst = wid * 1024;

  // ---- 32x32x16 fragment read offsets (swizzled) ----
  // A: row = wr*128 + mi*32 + (lane&31); chunk_s = ((lane>>5) ^ 2s) ^ (row&3)
  const int fr32 = lane & 31;
  const int hi = lane >> 5;
  const int c0 = (hi ^ (fr32 & 3)) << 4;  // s=0 chunk byte; s=1 = ^32
  const int abase = (wr * 128 + fr32) * 64 + c0;           // + mi*2048
  const int bbase = 16384 + (wc * 64 + fr32) * 64 + c0;    // + ni*2048

  f32x16 acc[4][2] = {};
  const int NT = K >> 5;

  auto STAGE_A = [&](int t, int b) {
    const size_t kby = (size_t)t * 64;
    char* base = SH + b * BUFB;
    glds16(Ag0 + kby, base + dst);
    glds16(Ag1 + kby, base + 8192 + dst);
  };
  auto STAGE_B = [&](int t, int b) {
    const size_t kby = (size_t)t * 64;
    char* base = SH + b * BUFB;
    glds16(Bg0 + kby, base + 16384 + dst);
    glds16(Bg1 + kby, base + 24576 + dst);
  };

  STAGE_A(0, 0); STAGE_B(0, 0);
  STAGE_A(1, 1); STAGE_B(1, 1);

  int b = 0;
  for (int t = 0; t < NT - 1; ++t) {
    const int b2 = (b == 0) ? 2 : b - 1;
    asm volatile("s_waitcnt vmcnt(4)" ::: "memory");  // tile t landed (t+1 in flight)
    __builtin_amdgcn_s_barrier();
    __builtin_amdgcn_sched_barrier(0);
    const char* bufp = SH + b * BUFB;
    // ---- phase 0: read A-frags 0,1 + all B-frags, stage A(t+2), MFMA mi 0,1 ----
    f16x8 afr[2][2], bfr[2][2];
#pragma unroll
    for (int mi = 0; mi < 2; ++mi) {
      const int ao = abase + mi * 2048;
      afr[mi][0] = *reinterpret_cast<const f16x8*>(bufp + ao);
      afr[mi][1] = *reinterpret_cast<const f16x8*>(bufp + (ao ^ 32));
    }
#pragma unroll
    for (int ni = 0; ni < 2; ++ni) {
      const int bo = bbase + ni * 2048;
      bfr[ni][0] = *reinterpret_cast<const f16x8*>(bufp + bo);
      bfr[ni][1] = *reinterpret_cast<const f16x8*>(bufp + (bo ^ 32));
    }
    if (t + 2 < NT) STAGE_A(t + 2, b2);
    __builtin_amdgcn_s_barrier();
    __builtin_amdgcn_sched_barrier(0);
    asm volatile("s_waitcnt lgkmcnt(0)" ::: "memory");
    __builtin_amdgcn_sched_barrier(0);
    __builtin_amdgcn_s_setprio(1);
#pragma unroll
    for (int s = 0; s < 2; ++s)
#pragma unroll
      for (int mi = 0; mi < 2; ++mi)
#pragma unroll
        for (int ni = 0; ni < 2; ++ni)
          acc[mi][ni] = __builtin_amdgcn_mfma_f32_32x32x16_f16(
              afr[mi][s], bfr[ni][s], acc[mi][ni], 0, 0, 0);
    __builtin_amdgcn_s_setprio(0);
    // ---- phase 1: read A-frags 2,3, stage B(t+2), MFMA mi 2,3 ----
    f16x8 agr[2][2];
#pragma unroll
    for (int mi = 0; mi < 2; ++mi) {
      const int ao = abase + (2 + mi) * 2048;
      agr[mi][0] = *reinterpret_cast<const f16x8*>(bufp + ao);
      agr[mi][1] = *reinterpret_cast<const f16x8*>(bufp + (ao ^ 32));
    }
    if (t + 2 < NT) STAGE_B(t + 2, b2);
    __builtin_amdgcn_s_barrier();
    __builtin_amdgcn_sched_barrier(0);
    asm volatile("s_waitcnt lgkmcnt(0)" ::: "memory");
    __builtin_amdgcn_sched_barrier(0);
    __builtin_amdgcn_s_setprio(1);
#pragma unroll
    for (int s = 0; s < 2; ++s)
#pragma unroll
      for (int mi = 0; mi < 2; ++mi)
#pragma unroll
        for (int ni = 0; ni < 2; ++ni)
          acc[2 + mi][ni] = __builtin_amdgcn_mfma_f32_32x32x16_f16(
              agr[mi][s], bfr[ni][s], acc[2 + mi][ni], 0, 0, 0);
    __builtin_amdgcn_s_setprio(0);
    b = (b == 2) ? 0 : b + 1;
  }
  // ---- peeled last tile ----
  {
    asm volatile("s_waitcnt vmcnt(0)" ::: "memory");
    __builtin_amdgcn_s_barrier();
    __builtin_amdgcn_sched_barrier(0);
    const char* bufp = SH + b * BUFB;
    f16x8 afr[4][2], bfr[2][2];
#pragma unroll
    for (int mi = 0; mi < 4; ++mi) {
      const int ao = abase + mi * 2048;
      afr[mi][0] = *reinterpret_cast<const f16x8*>(bufp + ao);
      afr[mi][1] = *reinterpret_cast<const f16x8*>(bufp + (ao ^ 32));
    }
#pragma unroll
    for (int ni = 0; ni < 2; ++ni) {
      const int bo = bbase + ni * 2048;
      bfr[ni][0] = *reinterpret_cast<const f16x8*>(bufp + bo);
      bfr[ni][1] = *reinterpret_cast<const f16x8*>(bufp + (bo ^ 32));
    }
#pragma unroll
    for (int s = 0; s < 2; ++s)
#pragma unroll
      for (int mi = 0; mi < 4; ++mi)
#pragma unroll
        for (int ni = 0; ni < 2; ++ni)
          acc[mi][ni] = __builtin_amdgcn_mfma_f32_32x32x16_f16(
              afr[mi][s], bfr[ni][s], acc[mi][ni], 0, 0, 0);
  }
  __syncthreads();

  // ---- epilogue via per-wave LDS transpose ----
  // C/D map (32x32): col = lane&31, row = (reg&3) + 8*(reg>>2) + 4*(lane>>5)
  f16* tb = (f16*)SH + wid * 2176;  // 32 x 68 f16 per wave
  const int colbase = bn + wc * 64;
  const int rrow = lane >> 3;       // readback: 0..7
  const int rcol = (lane & 7) * 8;  // 0..56

#pragma unroll
  for (int mi = 0; mi < 4; ++mi) {
#pragma unroll
    for (int ni = 0; ni < 2; ++ni)
#pragma unroll
      for (int q = 0; q < 4; ++q)
#pragma unroll
        for (int j = 0; j < 4; ++j)
          tb[(q * 8 + j + hi * 4) * 68 + ni * 32 + fr32] = (f16)acc[mi][ni][q * 4 + j];
    // same-wave DS ordering: reads observe the writes above
#pragma unroll
    for (int it = 0; it < 4; ++it) {
      const int row = rrow + it * 8;
      const int gm = bm + wr * 128 + mi * 32 + row;
      const int gn = colbase + rcol;
      f16x8 v = *reinterpret_cast<const f16x8*>(tb + row * 68 + rcol);
      if constexpr (EP == 0) {
        float4 b0 = *reinterpret_cast<const float4*>(ep.biasf + gn);
        float4 b1 = *reinterpret_cast<const float4*>(ep.biasf + gn + 4);
        f16x8 o;
        o[0] = (f16)((float)v[0] + b0.x); o[1] = (f16)((float)v[1] + b0.y);
        o[2] = (f16)((float)v[2] + b0.z); o[3] = (f16)((float)v[3] + b0.w);
        o[4] = (f16)((float)v[4] + b1.x); o[5] = (f16)((float)v[5] + b1.y);
        o[6] = (f16)((float)v[6] + b1.z); o[7] = (f16)((float)v[7] + b1.w);
        *reinterpret_cast<f16x8*>(ep.out_h + (size_t)gm * N + gn) = o;
      } else {
        f16x8 pr = *reinterpret_cast<const f16x8*>(ep.pre16 + (size_t)gm * 4096 + gn);
        if (colbase < 2048) {
          f16x8 hh = *reinterpret_cast<const f16x8*>(ep.h16 + (size_t)gm * 2048 + gn);
          f16x8 o;
#pragma unroll
          for (int k = 0; k < 8; ++k) {
            float u = (float)v[k] + (float)pr[k];
            o[k] = (f16)(tanh_fast(u) - (float)hh[k]);
          }
          *reinterpret_cast<f16x8*>(ep.out_d + (size_t)gm * 2048 + gn) = o;
        } else {
          f16x8 o;
#pragma unroll
          for (int k = 0; k < 8; ++k) {
            float u = (float)v[k] + (float)pr[k];
            o[k] = (f16)silu_fast(u);
          }
          *reinterpret_cast<f16x8*>(ep.out_h + (size_t)gm * 2048 + (gn - 2048)) = o;
        }
      }
    }
  }
}

// ================= 256x128 single-phase deep-pipeline GEMM (EP2, 16x16x32) =================
__global__ __launch_bounds__(512, 2)
void gemmC(const f16* __restrict__ A, const f16* __restrict__ Bw,
           int K, EpArgs ep) {
  constexpr int BUFB = 24576;  // A 16KB + B 8KB
  __shared__ __align__(16) char SH[BUFB * 3];  // 72 KB

  const int gx = gridDim.x;
  const int nwg = gx * gridDim.y;
  const int orig = blockIdx.y * gx + blockIdx.x;
  const int cpx = nwg >> 3;
  const int w = (orig & 7) * cpx + (orig >> 3);
  const int bm = (w % gx) * 256;
  const int bn = (w / gx) * 128;

  const int tid = threadIdx.x;
  const int lane = tid & 63;
  const int wid = tid >> 6;
  const int wr = wid >> 2;  // 0..1
  const int wc = wid & 3;   // 0..3

  const int srow = wid * 16 + (lane >> 2);
  const int skof = ((lane & 3) ^ ((lane >> 2) & 3)) << 4;
  const char* Ag0 = (const char*)A + (size_t)(bm + srow) * K * 2 + skof;
  const char* Ag1 = Ag0 + (size_t)128 * K * 2;
  const char* Bg0 = (const char*)Bw + (size_t)(bn + srow) * K * 2 + skof;
  const int dst = wid * 1024;

  const int fr = lane & 15;
  const int rxor = ((lane >> 4) ^ (fr & 3)) << 4;
  const int abase = (wr * 128 + fr) * 64 + rxor;
  const int bbase = 16384 + (wc * 32 + fr) * 64 + rxor;

  f32x4 acc[8][2] = {};
  const int NT = K >> 5;

  auto STAGE = [&](int t, int b) {
    const size_t kby = (size_t)t * 64;
    char* base = SH + b * BUFB;
    glds16(Ag0 + kby, base + dst);
    glds16(Ag1 + kby, base + 8192 + dst);
    glds16(Bg0 + kby, base + 16384 + dst);
  };

  STAGE(0, 0); STAGE(1, 1);

  int b = 0;
  for (int t = 0; t < NT - 1; ++t) {
    const int b2 = (b == 0) ? 2 : b - 1;
    asm volatile("s_waitcnt vmcnt(3)" ::: "memory");
    __builtin_amdgcn_s_barrier();
    __builtin_amdgcn_sched_barrier(0);
    const char* bufp = SH + b * BUFB;
    f16x8 af[8], bf[2];
#pragma unroll
    for (int i = 0; i < 8; ++i) af[i] = *reinterpret_cast<const f16x8*>(bufp + abase + i * 1024);
#pragma unroll
    for (int i = 0; i < 2; ++i) bf[i] = *reinterpret_cast<const f16x8*>(bufp + bbase + i * 1024);
    if (t + 2 < NT) STAGE(t + 2, b2);
    __builtin_amdgcn_s_barrier();
    __builtin_amdgcn_sched_barrier(0);
    asm volatile("s_waitcnt lgkmcnt(0)" ::: "memory");
    __builtin_amdgcn_sched_barrier(0);
    __builtin_amdgcn_s_setprio(1);
#pragma unroll
    for (int mi = 0; mi < 8; ++mi)
#pragma unroll
      for (int ni = 0; ni < 2; ++ni)
        acc[mi][ni] = __builtin_amdgcn_mfma_f32_16x16x32_f16(af[mi], bf[ni], acc[mi][ni], 0, 0, 0);
    __builtin_amdgcn_s_setprio(0);
    b = (b == 2) ? 0 : b + 1;
  }
  {
    asm volatile("s_waitcnt vmcnt(0)" ::: "memory");
    __builtin_amdgcn_s_barrier();
    __builtin_amdgcn_sched_barrier(0);
    const char* bufp = SH + b * BUFB;
    f16x8 af[8], bf[2];
#pragma unroll
    for (int i = 0; i < 8; ++i) af[i] = *reinterpret_cast<const f16x8*>(bufp + abase + i * 1024);
#pragma unroll
    for (int i = 0; i < 2; ++i) bf[i] = *reinterpret_cast<const f16x8*>(bufp + bbase + i * 1024);
#pragma unroll
    for (int mi = 0; mi < 8; ++mi)
#pragma unroll
      for (int ni = 0; ni < 2; ++ni)
        acc[mi][ni] = __builtin_amdgcn_mfma_f32_16x16x32_f16(af[mi], bf[ni], acc[mi][ni], 0, 0, 0);
  }
  __syncthreads();

  // ---- EP2 epilogue via per-wave LDS transpose (16x16 C/D map) ----
  f16* tb = (f16*)SH + wid * 576;  // 16x36 f16 per wave
  const int er = (lane >> 4) * 4;
  const int ec = lane & 15;
  const int rr = lane >> 2;        // 0..15
  const int cc = (lane & 3) * 8;   // 0..24
  const int colbase = bn + wc * 32;

#pragma unroll
  for (int mi = 0; mi < 8; ++mi) {
#pragma unroll
    for (int ni = 0; ni < 2; ++ni)
#pragma unroll
      for (int j = 0; j < 4; ++j)
        tb[(er + j) * 36 + ni * 16 + ec] = (f16)acc[mi][ni][j];
    const int row = rr;
    const int gm = bm + wr * 128 + mi * 16 + row;
    const int gn = colbase + cc;
    f16x8 v = *reinterpret_cast<const f16x8*>(tb + row * 36 + cc);
    const size_t idx = (size_t)gm * 2048 + gn;
    float4 b0 = *reinterpret_cast<const float4*>(ep.bt2 + gn);
    float4 b1 = *reinterpret_cast<const float4*>(ep.bt2 + gn + 4);
    f16x8 df = *reinterpret_cast<const f16x8*>(ep.diff + idx);
    f16x8 hbv = *reinterpret_cast<const f16x8*>(ep.hb16 + idx);
    float bb[8] = {b0.x, b0.y, b0.z, b0.w, b1.x, b1.y, b1.z, b1.w};
    f16x8 o16;
    float on[8];
#pragma unroll
    for (int k = 0; k < 8; ++k) {
      float u = (float)v[k] + bb[k];
      float tau = softplus_fast(u) + TAU_MIN_F;
      float hn = (float)hbv[k] + ep.coef * ((float)df[k] * rcp_fast(tau));
      on[k] = hn;
      o16[k] = (f16)hn;
    }
    *reinterpret_cast<f16x8*>(ep.out_h + idx) = o16;
    if (ep.out_f) {
      float4 o0 = {on[0], on[1], on[2], on[3]};
      float4 o1 = {on[4], on[5], on[6], on[7]};
      *reinterpret_cast<float4*>(ep.out_f + idx) = o0;
      *reinterpret_cast<float4*>(ep.out_f + idx + 4) = o1;
    }
  }
}

// ---------------- launch ----------------
extern "C" void kernel_launch(void* const* d_in, const int* in_sizes, int n_in,
                              void* d_out, int out_size, void* d_ws, size_t ws_size,
                              hipStream_t stream) {
  const float* x   = (const float*)d_in[0];
  const float* h   = (const float*)d_in[1];
  const float* Wih = (const float*)d_in[2];
  const float* bih = (const float*)d_in[3];
  const float* Whh = (const float*)d_in[4];
  const float* bhh = (const float*)d_in[5];
  const float* Wt1 = (const float*)d_in[6];
  const float* bt1 = (const float*)d_in[7];
  const float* Wt2 = (const float*)d_in[8];
  const float* bt2 = (const float*)d_in[9];
  float* hout = (float*)d_out;

  char* p = (char*)d_ws;
  auto alloc = [&](size_t bytes) {
    char* r = p;
    p += (bytes + 255) & ~(size_t)255;
    return r;
  };
  f16* xb    = (f16*)alloc((size_t)4096 * 1024 * 2);
  f16* Wpre  = (f16*)alloc((size_t)4096 * 1024 * 2);
  f16* Wab   = (f16*)alloc((size_t)4096 * 2048 * 2);
  f16* Wt2b  = (f16*)alloc((size_t)2048 * 2048 * 2);
  f16* hb    = (f16*)alloc((size_t)4096 * 2048 * 2);
  f16* hmb   = (f16*)alloc((size_t)4096 * 2048 * 2);
  f16* t1b   = (f16*)alloc((size_t)4096 * 2048 * 2);
  f16* pre16 = (f16*)alloc((size_t)4096 * 4096 * 2);
  f16* dif16 = (f16*)alloc((size_t)4096 * 2048 * 2);
  float* biasp = (float*)alloc(4096 * 4);

  prep_all<<<2048, 256, 0, stream>>>(x, h, Wih, Whh, Wt1, Wt2, bih, bhh, bt1,
                                     xb, hb, Wpre, Wab, Wt2b, biasp);

  // pre16 = f16(x @ [W_ih;W_t1x]^T + bias_pre)   (M=4096, N=4096, K=1024)
  {
    EpArgs e{};
    e.biasf = biasp;
    e.out_h = pre16;
    gemmT<0><<<dim3(16, 16), 512, 0, stream>>>(xb, Wpre, 4096, 1024, e);
  }

  const float dt = 1.0f / 3.0f;
  for (int s = 0; s < 3; ++s) {
    // k1 at h: EP1 then EP2 (h_mid = h + 0.5*dt*k1)
    {
      EpArgs e{};
      e.pre16 = pre16; e.h16 = hb; e.out_d = dif16; e.out_h = t1b;
      gemmT<1><<<dim3(16, 16), 512, 0, stream>>>(hb, Wab, 4096, 2048, e);
    }
    {
      EpArgs e{};
      e.bt2 = bt2; e.diff = dif16; e.hb16 = hb;
      e.coef = 0.5f * dt; e.out_f = nullptr; e.out_h = hmb;
      gemmC<<<dim3(16, 16), 512, 0, stream>>>(t1b, Wt2b, 2048, e);
    }
    // k2 at h_mid: EP1 then EP2 (h = h + dt*k2; in-place hb update safe per-lane)
    {
      EpArgs e{};
      e.pre16 = pre16; e.h16 = hmb; e.out_d = dif16; e.out_h = t1b;
      gemmT<1><<<dim3(16, 16), 512, 0, stream>>>(hmb, Wab, 4096, 2048, e);
    }
    {
      EpArgs e{};
      e.bt2 = bt2; e.diff = dif16; e.hb16 = hb;
      e.coef = dt; e.out_f = (s == 2) ? hout : nullptr; e.out_h = hb;
      gemmC<<<dim3(16, 16), 512, 0, stream>>>(t1b, Wt2b, 2048, e);
    }
  }
}

// Round 8
// 846.010 us; speedup vs baseline: 1.0703x; 1.0703x over previous
//
#include <hip/hip_runtime.h>

// LiquidODECell: B=4096, D_IN=1024, H=2048, TAU_MIN=0.2, 3 RK2 steps.
// f16 MFMA GEMMs (fp32 accum), fused LDS-transposed epilogues.
// gemmT: 256x256 2-phase deep pipeline, mfma_f32_16x16x32_f16 (EP0/EP1).
//   (32x32 shape variant measured SLOWER: bank conflicts 3x, reverted r7)
// gemmC: 256x128 single-phase deep pipeline, 16x16x32 (EP2 tau+RK2).
// prep_all: one fused grid-strided conversion/pack kernel.

typedef _Float16 f16;
typedef __attribute__((ext_vector_type(4))) _Float16 f16x4;
typedef __attribute__((ext_vector_type(8))) _Float16 f16x8;
typedef __attribute__((ext_vector_type(4))) float f32x4;

#define TAU_MIN_F 0.2f

__device__ __forceinline__ float rcp_fast(float x) { return __builtin_amdgcn_rcpf(x); }
__device__ __forceinline__ float tanh_fast(float u) {
  float t = __expf(2.0f * u);
  return 1.0f - 2.0f * rcp_fast(t + 1.0f);
}
__device__ __forceinline__ float silu_fast(float u) {
  return u * rcp_fast(1.0f + __expf(-u));
}
__device__ __forceinline__ float softplus_fast(float u) {
  return fmaxf(u, 0.0f) + __logf(1.0f + __expf(-fabsf(u)));
}

__device__ __forceinline__ void glds16(const void* g, void* l) {
  __builtin_amdgcn_global_load_lds(
      (const __attribute__((address_space(1))) unsigned int*)g,
      (__attribute__((address_space(3))) unsigned int*)l,
      16, 0, 0);
}

// ---------------- fused prep kernel ----------------
__device__ __forceinline__ void cvt_one(const float* __restrict__ s,
                                        f16* __restrict__ d, int i) {
  float4 v = reinterpret_cast<const float4*>(s)[i];
  f16x4 o = {(_Float16)v.x, (_Float16)v.y, (_Float16)v.z, (_Float16)v.w};
  reinterpret_cast<f16x4*>(d)[i] = o;
}

__global__ __launch_bounds__(256)
void prep_all(const float* __restrict__ x, const float* __restrict__ h,
              const float* __restrict__ Wih, const float* __restrict__ Whh,
              const float* __restrict__ Wt1, const float* __restrict__ Wt2,
              const float* __restrict__ bih, const float* __restrict__ bhh,
              const float* __restrict__ bt1,
              f16* __restrict__ xb, f16* __restrict__ hb,
              f16* __restrict__ Wpre, f16* __restrict__ Wab,
              f16* __restrict__ Wt2b, float* __restrict__ biasp) {
  const int E0 = 1048576;            // x -> xb
  const int E1 = E0 + 524288;        // Wih -> Wpre[0:2048]
  const int E2 = E1 + 1048576;       // Whh -> Wab[0:2048]
  const int E3 = E2 + 1048576;       // Wt2 -> Wt2b
  const int E4 = E3 + 2097152;       // h -> hb
  const int E5 = E4 + 1572864;       // Wt1 split
  const int E6 = E5 + 1024;          // biasp
  const int stride = gridDim.x * 256;
  for (int i = blockIdx.x * 256 + threadIdx.x; i < E6; i += stride) {
    if (i < E0) {
      cvt_one(x, xb, i);
    } else if (i < E1) {
      cvt_one(Wih, Wpre, i - E0);
    } else if (i < E2) {
      cvt_one(Whh, Wab, i - E1);
    } else if (i < E3) {
      cvt_one(Wt2, Wt2b, i - E2);
    } else if (i < E4) {
      cvt_one(h, hb, i - E3);
    } else if (i < E5) {
      int j = i - E4;
      int r = j / 768;
      int c4 = (j - r * 768) * 4;
      float4 v = reinterpret_cast<const float4*>(Wt1)[j];
      f16x4 o = {(_Float16)v.x, (_Float16)v.y, (_Float16)v.z, (_Float16)v.w};
      if (c4 < 1024)
        *reinterpret_cast<f16x4*>(Wpre + (size_t)(2048 + r) * 1024 + c4) = o;
      else
        *reinterpret_cast<f16x4*>(Wab + (size_t)(2048 + r) * 2048 + (c4 - 1024)) = o;
    } else {
      int k = (i - E5) * 4;
      float4 o;
      if (k < 2048) {
        float4 a = *reinterpret_cast<const float4*>(bih + k);
        float4 bv = *reinterpret_cast<const float4*>(bhh + k);
        o = {a.x + bv.x, a.y + bv.y, a.z + bv.z, a.w + bv.w};
      } else {
        o = *reinterpret_cast<const float4*>(bt1 + (k - 2048));
      }
      *reinterpret_cast<float4*>(biasp + k) = o;
    }
  }
}

struct EpArgs {
  const float* biasf;   // EP0: bias_pre[N]
  const f16* pre16;     // EP1: pre [M,4096] f16
  const f16* h16;       // EP1: h this dynamics is evaluated at (f16)
  f16* out_d;           // EP1: diff f16
  f16* out_h;           // EP0: pre16 out; EP1: t1 f16; EP2: h' f16
  const float* bt2;     // EP2
  const f16* diff;      // EP2
  const f16* hb16;      // EP2: RK2 base h (f16)
  float* out_f;         // EP2: fp32 h' out (nullable; final step only)
  float coef;           // EP2 (0.5*dt or dt)
};

// ================= 256x256 2-phase deep-pipeline GEMM, 16x16x32 (EP0/EP1) =================
template <int EP>
__global__ __launch_bounds__(512, 2)
void gemmT(const f16* __restrict__ A, const f16* __restrict__ Bw,
           int N, int K, EpArgs ep) {
  constexpr int BUFB = 32768;
  __shared__ __align__(16) char SH[BUFB * 3];  // 96 KB

  const int gx = gridDim.x;
  const int nwg = gx * gridDim.y;
  const int orig = blockIdx.y * gx + blockIdx.x;
  const int cpx = nwg >> 3;
  const int w = (orig & 7) * cpx + (orig >> 3);
  const int bm = (w % gx) * 256;
  const int bn = (w / gx) * 256;

  const int tid = threadIdx.x;
  const int lane = tid & 63;
  const int wid = tid >> 6;
  const int wr = wid >> 2;  // 0..1
  const int wc = wid & 3;   // 0..3

  const int srow = wid * 16 + (lane >> 2);                 // 0..127
  const int skof = ((lane & 3) ^ ((lane >> 2) & 3)) << 4;  // pre-swizzled src chunk
  const char* Ag0 = (const char*)A + (size_t)(bm + srow) * K * 2 + skof;
  const char* Ag1 = Ag0 + (size_t)128 * K * 2;
  const char* Bg0 = (const char*)Bw + (size_t)(bn + srow) * K * 2 + skof;
  const char* Bg1 = Bg0 + (size_t)128 * K * 2;
  const int dst = wid * 1024;

  const int fr = lane & 15;
  const int rxor = ((lane >> 4) ^ (fr & 3)) << 4;
  const int abase = (wr * 128 + fr) * 64 + rxor;
  const int bbase = 16384 + (wc * 64 + fr) * 64 + rxor;

  f32x4 acc[8][4] = {};
  const int NT = K >> 5;

  auto STAGE_A = [&](int t, int b) {
    const size_t kby = (size_t)t * 64;
    char* base = SH + b * BUFB;
    glds16(Ag0 + kby, base + dst);
    glds16(Ag1 + kby, base + 8192 + dst);
  };
  auto STAGE_B = [&](int t, int b) {
    const size_t kby = (size_t)t * 64;
    char* base = SH + b * BUFB;
    glds16(Bg0 + kby, base + 16384 + dst);
    glds16(Bg1 + kby, base + 24576 + dst);
  };

  STAGE_A(0, 0); STAGE_B(0, 0);
  STAGE_A(1, 1); STAGE_B(1, 1);

  int b = 0;
  for (int t = 0; t < NT - 1; ++t) {
    const int b2 = (b == 0) ? 2 : b - 1;
    asm volatile("s_waitcnt vmcnt(4)" ::: "memory");  // tile t landed (t+1 in flight)
    __builtin_amdgcn_s_barrier();
    __builtin_amdgcn_sched_barrier(0);
    const char* bufp = SH + b * BUFB;
    f16x8 af[4], bf[4];
#pragma unroll
    for (int i = 0; i < 4; ++i) af[i] = *reinterpret_cast<const f16x8*>(bufp + abase + i * 1024);
#pragma unroll
    for (int i = 0; i < 4; ++i) bf[i] = *reinterpret_cast<const f16x8*>(bufp + bbase + i * 1024);
    if (t + 2 < NT) STAGE_A(t + 2, b2);
    __builtin_amdgcn_s_barrier();
    __builtin_amdgcn_sched_barrier(0);
    asm volatile("s_waitcnt lgkmcnt(0)" ::: "memory");
    __builtin_amdgcn_sched_barrier(0);
    __builtin_amdgcn_s_setprio(1);
#pragma unroll
    for (int mi = 0; mi < 4; ++mi)
#pragma unroll
      for (int ni = 0; ni < 4; ++ni)
        acc[mi][ni] = __builtin_amdgcn_mfma_f32_16x16x32_f16(af[mi], bf[ni], acc[mi][ni], 0, 0, 0);
    __builtin_amdgcn_s_setprio(0);
    f16x8 ag[4];
#pragma unroll
    for (int i = 0; i < 4; ++i) ag[i] = *reinterpret_cast<const f16x8*>(bufp + abase + (4 + i) * 1024);
    if (t + 2 < NT) STAGE_B(t + 2, b2);
    __builtin_amdgcn_s_barrier();
    __builtin_amdgcn_sched_barrier(0);
    asm volatile("s_waitcnt lgkmcnt(0)" ::: "memory");
    __builtin_amdgcn_sched_barrier(0);
    __builtin_amdgcn_s_setprio(1);
#pragma unroll
    for (int mi = 0; mi < 4; ++mi)
#pragma unroll
      for (int ni = 0; ni < 4; ++ni)
        acc[4 + mi][ni] =
            __builtin_amdgcn_mfma_f32_16x16x32_f16(ag[mi], bf[ni], acc[4 + mi][ni], 0, 0, 0);
    __builtin_amdgcn_s_setprio(0);
    b = (b == 2) ? 0 : b + 1;
  }
  {
    asm volatile("s_waitcnt vmcnt(0)" ::: "memory");
    __builtin_amdgcn_s_barrier();
    __builtin_amdgcn_sched_barrier(0);
    const char* bufp = SH + b * BUFB;
    f16x8 af[4], bf[4];
#pragma unroll
    for (int i = 0; i < 4; ++i) af[i] = *reinterpret_cast<const f16x8*>(bufp + abase + i * 1024);
#pragma unroll
    for (int i = 0; i < 4; ++i) bf[i] = *reinterpret_cast<const f16x8*>(bufp + bbase + i * 1024);
#pragma unroll
    for (int mi = 0; mi < 4; ++mi)
#pragma unroll
      for (int ni = 0; ni < 4; ++ni)
        acc[mi][ni] = __builtin_amdgcn_mfma_f32_16x16x32_f16(af[mi], bf[ni], acc[mi][ni], 0, 0, 0);
    f16x8 ag[4];
#pragma unroll
    for (int i = 0; i < 4; ++i) ag[i] = *reinterpret_cast<const f16x8*>(bufp + abase + (4 + i) * 1024);
#pragma unroll
    for (int mi = 0; mi < 4; ++mi)
#pragma unroll
      for (int ni = 0; ni < 4; ++ni)
        acc[4 + mi][ni] =
            __builtin_amdgcn_mfma_f32_16x16x32_f16(ag[mi], bf[ni], acc[4 + mi][ni], 0, 0, 0);
  }
  __syncthreads();

  // ---- epilogue via per-wave LDS transpose ----
  f16* tb = (f16*)SH + wid * 1088;  // 16x68
  const int er = (lane >> 4) * 4;
  const int ec = lane & 15;
  const int rr = lane >> 3;
  const int cc = (lane & 7) * 8;
  const int colbase = bn + wc * 64;

#pragma unroll
  for (int mi = 0; mi < 8; ++mi) {
#pragma unroll
    for (int ni = 0; ni < 4; ++ni)
#pragma unroll
      for (int j = 0; j < 4; ++j)
        tb[(er + j) * 68 + ni * 16 + ec] = (f16)acc[mi][ni][j];
#pragma unroll
    for (int it = 0; it < 2; ++it) {
      const int row = rr + it * 8;
      const int gm = bm + wr * 128 + mi * 16 + row;
      const int gn = colbase + cc;
      f16x8 v = *reinterpret_cast<const f16x8*>(tb + row * 68 + cc);
      if constexpr (EP == 0) {
        float4 b0 = *reinterpret_cast<const float4*>(ep.biasf + gn);
        float4 b1 = *reinterpret_cast<const float4*>(ep.biasf + gn + 4);
        f16x8 o;
        o[0] = (f16)((float)v[0] + b0.x); o[1] = (f16)((float)v[1] + b0.y);
        o[2] = (f16)((float)v[2] + b0.z); o[3] = (f16)((float)v[3] + b0.w);
        o[4] = (f16)((float)v[4] + b1.x); o[5] = (f16)((float)v[5] + b1.y);
        o[6] = (f16)((float)v[6] + b1.z); o[7] = (f16)((float)v[7] + b1.w);
        *reinterpret_cast<f16x8*>(ep.out_h + (size_t)gm * N + gn) = o;
      } else {
        f16x8 pr = *reinterpret_cast<const f16x8*>(ep.pre16 + (size_t)gm * 4096 + gn);
        if (colbase < 2048) {
          f16x8 hh = *reinterpret_cast<const f16x8*>(ep.h16 + (size_t)gm * 2048 + gn);
          f16x8 o;
#pragma unroll
          for (int k = 0; k < 8; ++k) {
            float u = (float)v[k] + (float)pr[k];
            o[k] = (f16)(tanh_fast(u) - (float)hh[k]);
          }
          *reinterpret_cast<f16x8*>(ep.out_d + (size_t)gm * 2048 + gn) = o;
        } else {
          f16x8 o;
#pragma unroll
          for (int k = 0; k < 8; ++k) {
            float u = (float)v[k] + (float)pr[k];
            o[k] = (f16)silu_fast(u);
          }
          *reinterpret_cast<f16x8*>(ep.out_h + (size_t)gm * 2048 + (gn - 2048)) = o;
        }
      }
    }
  }
}

// ================= 256x128 single-phase deep-pipeline GEMM (EP2, 16x16x32) =================
__global__ __launch_bounds__(512, 2)
void gemmC(const f16* __restrict__ A, const f16* __restrict__ Bw,
           int K, EpArgs ep) {
  constexpr int BUFB = 24576;  // A 16KB + B 8KB
  __shared__ __align__(16) char SH[BUFB * 3];  // 72 KB

  const int gx = gridDim.x;
  const int nwg = gx * gridDim.y;
  const int orig = blockIdx.y * gx + blockIdx.x;
  const int cpx = nwg >> 3;
  const int w = (orig & 7) * cpx + (orig >> 3);
  const int bm = (w % gx) * 256;
  const int bn = (w / gx) * 128;

  const int tid = threadIdx.x;
  const int lane = tid & 63;
  const int wid = tid >> 6;
  const int wr = wid >> 2;  // 0..1
  const int wc = wid & 3;   // 0..3

  const int srow = wid * 16 + (lane >> 2);
  const int skof = ((lane & 3) ^ ((lane >> 2) & 3)) << 4;
  const char* Ag0 = (const char*)A + (size_t)(bm + srow) * K * 2 + skof;
  const char* Ag1 = Ag0 + (size_t)128 * K * 2;
  const char* Bg0 = (const char*)Bw + (size_t)(bn + srow) * K * 2 + skof;
  const int dst = wid * 1024;

  const int fr = lane & 15;
  const int rxor = ((lane >> 4) ^ (fr & 3)) << 4;
  const int abase = (wr * 128 + fr) * 64 + rxor;
  const int bbase = 16384 + (wc * 32 + fr) * 64 + rxor;

  f32x4 acc[8][2] = {};
  const int NT = K >> 5;

  auto STAGE = [&](int t, int b) {
    const size_t kby = (size_t)t * 64;
    char* base = SH + b * BUFB;
    glds16(Ag0 + kby, base + dst);
    glds16(Ag1 + kby, base + 8192 + dst);
    glds16(Bg0 + kby, base + 16384 + dst);
  };

  STAGE(0, 0); STAGE(1, 1);

  int b = 0;
  for (int t = 0; t < NT - 1; ++t) {
    const int b2 = (b == 0) ? 2 : b - 1;
    asm volatile("s_waitcnt vmcnt(3)" ::: "memory");
    __builtin_amdgcn_s_barrier();
    __builtin_amdgcn_sched_barrier(0);
    const char* bufp = SH + b * BUFB;
    f16x8 af[8], bf[2];
#pragma unroll
    for (int i = 0; i < 8; ++i) af[i] = *reinterpret_cast<const f16x8*>(bufp + abase + i * 1024);
#pragma unroll
    for (int i = 0; i < 2; ++i) bf[i] = *reinterpret_cast<const f16x8*>(bufp + bbase + i * 1024);
    if (t + 2 < NT) STAGE(t + 2, b2);
    __builtin_amdgcn_s_barrier();
    __builtin_amdgcn_sched_barrier(0);
    asm volatile("s_waitcnt lgkmcnt(0)" ::: "memory");
    __builtin_amdgcn_sched_barrier(0);
    __builtin_amdgcn_s_setprio(1);
#pragma unroll
    for (int mi = 0; mi < 8; ++mi)
#pragma unroll
      for (int ni = 0; ni < 2; ++ni)
        acc[mi][ni] = __builtin_amdgcn_mfma_f32_16x16x32_f16(af[mi], bf[ni], acc[mi][ni], 0, 0, 0);
    __builtin_amdgcn_s_setprio(0);
    b = (b == 2) ? 0 : b + 1;
  }
  {
    asm volatile("s_waitcnt vmcnt(0)" ::: "memory");
    __builtin_amdgcn_s_barrier();
    __builtin_amdgcn_sched_barrier(0);
    const char* bufp = SH + b * BUFB;
    f16x8 af[8], bf[2];
#pragma unroll
    for (int i = 0; i < 8; ++i) af[i] = *reinterpret_cast<const f16x8*>(bufp + abase + i * 1024);
#pragma unroll
    for (int i = 0; i < 2; ++i) bf[i] = *reinterpret_cast<const f16x8*>(bufp + bbase + i * 1024);
#pragma unroll
    for (int mi = 0; mi < 8; ++mi)
#pragma unroll
      for (int ni = 0; ni < 2; ++ni)
        acc[mi][ni] = __builtin_amdgcn_mfma_f32_16x16x32_f16(af[mi], bf[ni], acc[mi][ni], 0, 0, 0);
  }
  __syncthreads();

  // ---- EP2 epilogue via per-wave LDS transpose ----
  f16* tb = (f16*)SH + wid * 576;  // 16x36 f16 per wave
  const int er = (lane >> 4) * 4;
  const int ec = lane & 15;
  const int rr = lane >> 2;        // 0..15
  const int cc = (lane & 3) * 8;   // 0..24
  const int colbase = bn + wc * 32;

#pragma unroll
  for (int mi = 0; mi < 8; ++mi) {
#pragma unroll
    for (int ni = 0; ni < 2; ++ni)
#pragma unroll
      for (int j = 0; j < 4; ++j)
        tb[(er + j) * 36 + ni * 16 + ec] = (f16)acc[mi][ni][j];
    const int row = rr;
    const int gm = bm + wr * 128 + mi * 16 + row;
    const int gn = colbase + cc;
    f16x8 v = *reinterpret_cast<const f16x8*>(tb + row * 36 + cc);
    const size_t idx = (size_t)gm * 2048 + gn;
    float4 b0 = *reinterpret_cast<const float4*>(ep.bt2 + gn);
    float4 b1 = *reinterpret_cast<const float4*>(ep.bt2 + gn + 4);
    f16x8 df = *reinterpret_cast<const f16x8*>(ep.diff + idx);
    f16x8 hbv = *reinterpret_cast<const f16x8*>(ep.hb16 + idx);
    float bb[8] = {b0.x, b0.y, b0.z, b0.w, b1.x, b1.y, b1.z, b1.w};
    float on[8];
#pragma unroll
    for (int k = 0; k < 8; ++k) {
      float u = (float)v[k] + bb[k];
      float tau = softplus_fast(u) + TAU_MIN_F;
      on[k] = (float)hbv[k] + ep.coef * ((float)df[k] * rcp_fast(tau));
    }
    if (ep.out_f) {
      float4 o0 = {on[0], on[1], on[2], on[3]};
      float4 o1 = {on[4], on[5], on[6], on[7]};
      *reinterpret_cast<float4*>(ep.out_f + idx) = o0;
      *reinterpret_cast<float4*>(ep.out_f + idx + 4) = o1;
    } else {
      f16x8 o16;
#pragma unroll
      for (int k = 0; k < 8; ++k) o16[k] = (f16)on[k];
      *reinterpret_cast<f16x8*>(ep.out_h + idx) = o16;
    }
  }
}

// ---------------- launch ----------------
extern "C" void kernel_launch(void* const* d_in, const int* in_sizes, int n_in,
                              void* d_out, int out_size, void* d_ws, size_t ws_size,
                              hipStream_t stream) {
  const float* x   = (const float*)d_in[0];
  const float* h   = (const float*)d_in[1];
  const float* Wih = (const float*)d_in[2];
  const float* bih = (const float*)d_in[3];
  const float* Whh = (const float*)d_in[4];
  const float* bhh = (const float*)d_in[5];
  const float* Wt1 = (const float*)d_in[6];
  const float* bt1 = (const float*)d_in[7];
  const float* Wt2 = (const float*)d_in[8];
  const float* bt2 = (const float*)d_in[9];
  float* hout = (float*)d_out;

  char* p = (char*)d_ws;
  auto alloc = [&](size_t bytes) {
    char* r = p;
    p += (bytes + 255) & ~(size_t)255;
    return r;
  };
  f16* xb    = (f16*)alloc((size_t)4096 * 1024 * 2);
  f16* Wpre  = (f16*)alloc((size_t)4096 * 1024 * 2);
  f16* Wab   = (f16*)alloc((size_t)4096 * 2048 * 2);
  f16* Wt2b  = (f16*)alloc((size_t)2048 * 2048 * 2);
  f16* hb    = (f16*)alloc((size_t)4096 * 2048 * 2);
  f16* hmb   = (f16*)alloc((size_t)4096 * 2048 * 2);
  f16* t1b   = (f16*)alloc((size_t)4096 * 2048 * 2);
  f16* pre16 = (f16*)alloc((size_t)4096 * 4096 * 2);
  f16* dif16 = (f16*)alloc((size_t)4096 * 2048 * 2);
  float* biasp = (float*)alloc(4096 * 4);

  prep_all<<<2048, 256, 0, stream>>>(x, h, Wih, Whh, Wt1, Wt2, bih, bhh, bt1,
                                     xb, hb, Wpre, Wab, Wt2b, biasp);

  // pre16 = f16(x @ [W_ih;W_t1x]^T + bias_pre)   (M=4096, N=4096, K=1024)
  {
    EpArgs e{};
    e.biasf = biasp;
    e.out_h = pre16;
    gemmT<0><<<dim3(16, 16), 512, 0, stream>>>(xb, Wpre, 4096, 1024, e);
  }

  const float dt = 1.0f / 3.0f;
  for (int s = 0; s < 3; ++s) {
    // k1 at h: EP1 then EP2 (h_mid = h + 0.5*dt*k1)
    {
      EpArgs e{};
      e.pre16 = pre16; e.h16 = hb; e.out_d = dif16; e.out_h = t1b;
      gemmT<1><<<dim3(16, 16), 512, 0, stream>>>(hb, Wab, 4096, 2048, e);
    }
    {
      EpArgs e{};
      e.bt2 = bt2; e.diff = dif16; e.hb16 = hb;
      e.coef = 0.5f * dt; e.out_f = nullptr; e.out_h = hmb;
      gemmC<<<dim3(16, 16), 512, 0, stream>>>(t1b, Wt2b, 2048, e);
    }
    // k2 at h_mid: EP1 then EP2 (h = h + dt*k2; in-place hb update safe per-lane)
    {
      EpArgs e{};
      e.pre16 = pre16; e.h16 = hmb; e.out_d = dif16; e.out_h = t1b;
      gemmT<1><<<dim3(16, 16), 512, 0, stream>>>(hmb, Wab, 4096, 2048, e);
    }
    {
      EpArgs e{};
      e.bt2 = bt2; e.diff = dif16; e.hb16 = hb;
      e.coef = dt; e.out_f = (s == 2) ? hout : nullptr; e.out_h = hb;
      gemmC<<<dim3(16, 16), 512, 0, stream>>>(t1b, Wt2b, 2048, e);
    }
  }
}

// Round 9
// 827.123 us; speedup vs baseline: 1.0947x; 1.0228x over previous
//
#include <hip/hip_runtime.h>

// LiquidODECell: B=4096, D_IN=1024, H=2048, TAU_MIN=0.2, 3 RK2 steps.
// f16 MFMA GEMMs (fp32 accum), fused LDS-transposed epilogues.
// gemmT: 256x256 2-phase deep pipeline, mfma_f32_16x16x32_f16 (EP0/EP1).
//   (32x32 shape variant measured SLOWER: bank conflicts 3x, reverted r7)
// gemmC: 128x256 single-phase deep pipeline (EP2 tau+RK2), per-wave 64x64
//   (flipped from 256x128 in r8: LDS-read:MFMA ratio 0.625 -> 0.5)
// prep_all: one fused grid-strided conversion/pack kernel.

typedef _Float16 f16;
typedef __attribute__((ext_vector_type(4))) _Float16 f16x4;
typedef __attribute__((ext_vector_type(8))) _Float16 f16x8;
typedef __attribute__((ext_vector_type(4))) float f32x4;

#define TAU_MIN_F 0.2f

__device__ __forceinline__ float rcp_fast(float x) { return __builtin_amdgcn_rcpf(x); }
__device__ __forceinline__ float tanh_fast(float u) {
  float t = __expf(2.0f * u);
  return 1.0f - 2.0f * rcp_fast(t + 1.0f);
}
__device__ __forceinline__ float silu_fast(float u) {
  return u * rcp_fast(1.0f + __expf(-u));
}
__device__ __forceinline__ float softplus_fast(float u) {
  return fmaxf(u, 0.0f) + __logf(1.0f + __expf(-fabsf(u)));
}

__device__ __forceinline__ void glds16(const void* g, void* l) {
  __builtin_amdgcn_global_load_lds(
      (const __attribute__((address_space(1))) unsigned int*)g,
      (__attribute__((address_space(3))) unsigned int*)l,
      16, 0, 0);
}

// ---------------- fused prep kernel ----------------
__device__ __forceinline__ void cvt_one(const float* __restrict__ s,
                                        f16* __restrict__ d, int i) {
  float4 v = reinterpret_cast<const float4*>(s)[i];
  f16x4 o = {(_Float16)v.x, (_Float16)v.y, (_Float16)v.z, (_Float16)v.w};
  reinterpret_cast<f16x4*>(d)[i] = o;
}

__global__ __launch_bounds__(256)
void prep_all(const float* __restrict__ x, const float* __restrict__ h,
              const float* __restrict__ Wih, const float* __restrict__ Whh,
              const float* __restrict__ Wt1, const float* __restrict__ Wt2,
              const float* __restrict__ bih, const float* __restrict__ bhh,
              const float* __restrict__ bt1,
              f16* __restrict__ xb, f16* __restrict__ hb,
              f16* __restrict__ Wpre, f16* __restrict__ Wab,
              f16* __restrict__ Wt2b, float* __restrict__ biasp) {
  const int E0 = 1048576;            // x -> xb
  const int E1 = E0 + 524288;        // Wih -> Wpre[0:2048]
  const int E2 = E1 + 1048576;       // Whh -> Wab[0:2048]
  const int E3 = E2 + 1048576;       // Wt2 -> Wt2b
  const int E4 = E3 + 2097152;       // h -> hb
  const int E5 = E4 + 1572864;       // Wt1 split
  const int E6 = E5 + 1024;          // biasp
  const int stride = gridDim.x * 256;
  for (int i = blockIdx.x * 256 + threadIdx.x; i < E6; i += stride) {
    if (i < E0) {
      cvt_one(x, xb, i);
    } else if (i < E1) {
      cvt_one(Wih, Wpre, i - E0);
    } else if (i < E2) {
      cvt_one(Whh, Wab, i - E1);
    } else if (i < E3) {
      cvt_one(Wt2, Wt2b, i - E2);
    } else if (i < E4) {
      cvt_one(h, hb, i - E3);
    } else if (i < E5) {
      int j = i - E4;
      int r = j / 768;
      int c4 = (j - r * 768) * 4;
      float4 v = reinterpret_cast<const float4*>(Wt1)[j];
      f16x4 o = {(_Float16)v.x, (_Float16)v.y, (_Float16)v.z, (_Float16)v.w};
      if (c4 < 1024)
        *reinterpret_cast<f16x4*>(Wpre + (size_t)(2048 + r) * 1024 + c4) = o;
      else
        *reinterpret_cast<f16x4*>(Wab + (size_t)(2048 + r) * 2048 + (c4 - 1024)) = o;
    } else {
      int k = (i - E5) * 4;
      float4 o;
      if (k < 2048) {
        float4 a = *reinterpret_cast<const float4*>(bih + k);
        float4 bv = *reinterpret_cast<const float4*>(bhh + k);
        o = {a.x + bv.x, a.y + bv.y, a.z + bv.z, a.w + bv.w};
      } else {
        o = *reinterpret_cast<const float4*>(bt1 + (k - 2048));
      }
      *reinterpret_cast<float4*>(biasp + k) = o;
    }
  }
}

struct EpArgs {
  const float* biasf;   // EP0: bias_pre[N]
  const f16* pre16;     // EP1: pre [M,4096] f16
  const f16* h16;       // EP1: h this dynamics is evaluated at (f16)
  f16* out_d;           // EP1: diff f16
  f16* out_h;           // EP0: pre16 out; EP1: t1 f16; EP2: h' f16
  const float* bt2;     // EP2
  const f16* diff;      // EP2
  const f16* hb16;      // EP2: RK2 base h (f16)
  float* out_f;         // EP2: fp32 h' out (nullable; final step only)
  float coef;           // EP2 (0.5*dt or dt)
};

// ================= 256x256 2-phase deep-pipeline GEMM, 16x16x32 (EP0/EP1) =================
template <int EP>
__global__ __launch_bounds__(512, 2)
void gemmT(const f16* __restrict__ A, const f16* __restrict__ Bw,
           int N, int K, EpArgs ep) {
  constexpr int BUFB = 32768;
  __shared__ __align__(16) char SH[BUFB * 3];  // 96 KB

  const int gx = gridDim.x;
  const int nwg = gx * gridDim.y;
  const int orig = blockIdx.y * gx + blockIdx.x;
  const int cpx = nwg >> 3;
  const int w = (orig & 7) * cpx + (orig >> 3);
  const int bm = (w % gx) * 256;
  const int bn = (w / gx) * 256;

  const int tid = threadIdx.x;
  const int lane = tid & 63;
  const int wid = tid >> 6;
  const int wr = wid >> 2;  // 0..1
  const int wc = wid & 3;   // 0..3

  const int srow = wid * 16 + (lane >> 2);                 // 0..127
  const int skof = ((lane & 3) ^ ((lane >> 2) & 3)) << 4;  // pre-swizzled src chunk
  const char* Ag0 = (const char*)A + (size_t)(bm + srow) * K * 2 + skof;
  const char* Ag1 = Ag0 + (size_t)128 * K * 2;
  const char* Bg0 = (const char*)Bw + (size_t)(bn + srow) * K * 2 + skof;
  const char* Bg1 = Bg0 + (size_t)128 * K * 2;
  const int dst = wid * 1024;

  const int fr = lane & 15;
  const int rxor = ((lane >> 4) ^ (fr & 3)) << 4;
  const int abase = (wr * 128 + fr) * 64 + rxor;
  const int bbase = 16384 + (wc * 64 + fr) * 64 + rxor;

  f32x4 acc[8][4] = {};
  const int NT = K >> 5;

  auto STAGE_A = [&](int t, int b) {
    const size_t kby = (size_t)t * 64;
    char* base = SH + b * BUFB;
    glds16(Ag0 + kby, base + dst);
    glds16(Ag1 + kby, base + 8192 + dst);
  };
  auto STAGE_B = [&](int t, int b) {
    const size_t kby = (size_t)t * 64;
    char* base = SH + b * BUFB;
    glds16(Bg0 + kby, base + 16384 + dst);
    glds16(Bg1 + kby, base + 24576 + dst);
  };

  STAGE_A(0, 0); STAGE_B(0, 0);
  STAGE_A(1, 1); STAGE_B(1, 1);

  int b = 0;
  for (int t = 0; t < NT - 1; ++t) {
    const int b2 = (b == 0) ? 2 : b - 1;
    asm volatile("s_waitcnt vmcnt(4)" ::: "memory");  // tile t landed (t+1 in flight)
    __builtin_amdgcn_s_barrier();
    __builtin_amdgcn_sched_barrier(0);
    const char* bufp = SH + b * BUFB;
    f16x8 af[4], bf[4];
#pragma unroll
    for (int i = 0; i < 4; ++i) af[i] = *reinterpret_cast<const f16x8*>(bufp + abase + i * 1024);
#pragma unroll
    for (int i = 0; i < 4; ++i) bf[i] = *reinterpret_cast<const f16x8*>(bufp + bbase + i * 1024);
    if (t + 2 < NT) STAGE_A(t + 2, b2);
    __builtin_amdgcn_s_barrier();
    __builtin_amdgcn_sched_barrier(0);
    asm volatile("s_waitcnt lgkmcnt(0)" ::: "memory");
    __builtin_amdgcn_sched_barrier(0);
    __builtin_amdgcn_s_setprio(1);
#pragma unroll
    for (int mi = 0; mi < 4; ++mi)
#pragma unroll
      for (int ni = 0; ni < 4; ++ni)
        acc[mi][ni] = __builtin_amdgcn_mfma_f32_16x16x32_f16(af[mi], bf[ni], acc[mi][ni], 0, 0, 0);
    __builtin_amdgcn_s_setprio(0);
    f16x8 ag[4];
#pragma unroll
    for (int i = 0; i < 4; ++i) ag[i] = *reinterpret_cast<const f16x8*>(bufp + abase + (4 + i) * 1024);
    if (t + 2 < NT) STAGE_B(t + 2, b2);
    __builtin_amdgcn_s_barrier();
    __builtin_amdgcn_sched_barrier(0);
    asm volatile("s_waitcnt lgkmcnt(0)" ::: "memory");
    __builtin_amdgcn_sched_barrier(0);
    __builtin_amdgcn_s_setprio(1);
#pragma unroll
    for (int mi = 0; mi < 4; ++mi)
#pragma unroll
      for (int ni = 0; ni < 4; ++ni)
        acc[4 + mi][ni] =
            __builtin_amdgcn_mfma_f32_16x16x32_f16(ag[mi], bf[ni], acc[4 + mi][ni], 0, 0, 0);
    __builtin_amdgcn_s_setprio(0);
    b = (b == 2) ? 0 : b + 1;
  }
  {
    asm volatile("s_waitcnt vmcnt(0)" ::: "memory");
    __builtin_amdgcn_s_barrier();
    __builtin_amdgcn_sched_barrier(0);
    const char* bufp = SH + b * BUFB;
    f16x8 af[4], bf[4];
#pragma unroll
    for (int i = 0; i < 4; ++i) af[i] = *reinterpret_cast<const f16x8*>(bufp + abase + i * 1024);
#pragma unroll
    for (int i = 0; i < 4; ++i) bf[i] = *reinterpret_cast<const f16x8*>(bufp + bbase + i * 1024);
#pragma unroll
    for (int mi = 0; mi < 4; ++mi)
#pragma unroll
      for (int ni = 0; ni < 4; ++ni)
        acc[mi][ni] = __builtin_amdgcn_mfma_f32_16x16x32_f16(af[mi], bf[ni], acc[mi][ni], 0, 0, 0);
    f16x8 ag[4];
#pragma unroll
    for (int i = 0; i < 4; ++i) ag[i] = *reinterpret_cast<const f16x8*>(bufp + abase + (4 + i) * 1024);
#pragma unroll
    for (int mi = 0; mi < 4; ++mi)
#pragma unroll
      for (int ni = 0; ni < 4; ++ni)
        acc[4 + mi][ni] =
            __builtin_amdgcn_mfma_f32_16x16x32_f16(ag[mi], bf[ni], acc[4 + mi][ni], 0, 0, 0);
  }
  __syncthreads();

  // ---- epilogue via per-wave LDS transpose ----
  f16* tb = (f16*)SH + wid * 1088;  // 16x68
  const int er = (lane >> 4) * 4;
  const int ec = lane & 15;
  const int rr = lane >> 3;
  const int cc = (lane & 7) * 8;
  const int colbase = bn + wc * 64;

#pragma unroll
  for (int mi = 0; mi < 8; ++mi) {
#pragma unroll
    for (int ni = 0; ni < 4; ++ni)
#pragma unroll
      for (int j = 0; j < 4; ++j)
        tb[(er + j) * 68 + ni * 16 + ec] = (f16)acc[mi][ni][j];
#pragma unroll
    for (int it = 0; it < 2; ++it) {
      const int row = rr + it * 8;
      const int gm = bm + wr * 128 + mi * 16 + row;
      const int gn = colbase + cc;
      f16x8 v = *reinterpret_cast<const f16x8*>(tb + row * 68 + cc);
      if constexpr (EP == 0) {
        float4 b0 = *reinterpret_cast<const float4*>(ep.biasf + gn);
        float4 b1 = *reinterpret_cast<const float4*>(ep.biasf + gn + 4);
        f16x8 o;
        o[0] = (f16)((float)v[0] + b0.x); o[1] = (f16)((float)v[1] + b0.y);
        o[2] = (f16)((float)v[2] + b0.z); o[3] = (f16)((float)v[3] + b0.w);
        o[4] = (f16)((float)v[4] + b1.x); o[5] = (f16)((float)v[5] + b1.y);
        o[6] = (f16)((float)v[6] + b1.z); o[7] = (f16)((float)v[7] + b1.w);
        *reinterpret_cast<f16x8*>(ep.out_h + (size_t)gm * N + gn) = o;
      } else {
        f16x8 pr = *reinterpret_cast<const f16x8*>(ep.pre16 + (size_t)gm * 4096 + gn);
        if (colbase < 2048) {
          f16x8 hh = *reinterpret_cast<const f16x8*>(ep.h16 + (size_t)gm * 2048 + gn);
          f16x8 o;
#pragma unroll
          for (int k = 0; k < 8; ++k) {
            float u = (float)v[k] + (float)pr[k];
            o[k] = (f16)(tanh_fast(u) - (float)hh[k]);
          }
          *reinterpret_cast<f16x8*>(ep.out_d + (size_t)gm * 2048 + gn) = o;
        } else {
          f16x8 o;
#pragma unroll
          for (int k = 0; k < 8; ++k) {
            float u = (float)v[k] + (float)pr[k];
            o[k] = (f16)silu_fast(u);
          }
          *reinterpret_cast<f16x8*>(ep.out_h + (size_t)gm * 2048 + (gn - 2048)) = o;
        }
      }
    }
  }
}

// ================= 128x256 single-phase deep-pipeline GEMM (EP2, 16x16x32) =================
// 8 waves (2M x 4N), per-wave 64x64. LDS buf: A 8KB + B 16KB = 24KB, x3 = 72KB.
__global__ __launch_bounds__(512, 2)
void gemmC(const f16* __restrict__ A, const f16* __restrict__ Bw,
           int K, EpArgs ep) {
  constexpr int BUFB = 24576;
  __shared__ __align__(16) char SH[BUFB * 3];  // 72 KB

  const int gx = gridDim.x;  // 32 (M tiles of 128)
  const int nwg = gx * gridDim.y;
  const int orig = blockIdx.y * gx + blockIdx.x;
  const int cpx = nwg >> 3;
  const int w = (orig & 7) * cpx + (orig >> 3);
  const int bm = (w % gx) * 128;
  const int bn = (w / gx) * 256;

  const int tid = threadIdx.x;
  const int lane = tid & 63;
  const int wid = tid >> 6;
  const int wr = wid >> 2;  // 0..1
  const int wc = wid & 3;   // 0..3

  const int srow = wid * 16 + (lane >> 2);                 // 0..127
  const int skof = ((lane & 3) ^ ((lane >> 2) & 3)) << 4;
  const char* Ag0 = (const char*)A + (size_t)(bm + srow) * K * 2 + skof;
  const char* Bg0 = (const char*)Bw + (size_t)(bn + srow) * K * 2 + skof;
  const char* Bg1 = Bg0 + (size_t)128 * K * 2;
  const int dst = wid * 1024;

  const int fr = lane & 15;
  const int rxor = ((lane >> 4) ^ (fr & 3)) << 4;
  const int abase = (wr * 64 + fr) * 64 + rxor;            // A: 128 rows at offset 0
  const int bbase = 8192 + (wc * 64 + fr) * 64 + rxor;     // B: 256 rows at offset 8K

  f32x4 acc[4][4] = {};
  const int NT = K >> 5;

  auto STAGE = [&](int t, int b) {
    const size_t kby = (size_t)t * 64;
    char* base = SH + b * BUFB;
    glds16(Ag0 + kby, base + dst);
    glds16(Bg0 + kby, base + 8192 + dst);
    glds16(Bg1 + kby, base + 16384 + dst);
  };

  STAGE(0, 0); STAGE(1, 1);

  int b = 0;
  for (int t = 0; t < NT - 1; ++t) {
    const int b2 = (b == 0) ? 2 : b - 1;
    asm volatile("s_waitcnt vmcnt(3)" ::: "memory");  // tile t landed (t+1 in flight)
    __builtin_amdgcn_s_barrier();
    __builtin_amdgcn_sched_barrier(0);
    const char* bufp = SH + b * BUFB;
    f16x8 af[4], bf[4];
#pragma unroll
    for (int i = 0; i < 4; ++i) af[i] = *reinterpret_cast<const f16x8*>(bufp + abase + i * 1024);
#pragma unroll
    for (int i = 0; i < 4; ++i) bf[i] = *reinterpret_cast<const f16x8*>(bufp + bbase + i * 1024);
    if (t + 2 < NT) STAGE(t + 2, b2);
    __builtin_amdgcn_s_barrier();
    __builtin_amdgcn_sched_barrier(0);
    asm volatile("s_waitcnt lgkmcnt(0)" ::: "memory");
    __builtin_amdgcn_sched_barrier(0);
    __builtin_amdgcn_s_setprio(1);
#pragma unroll
    for (int mi = 0; mi < 4; ++mi)
#pragma unroll
      for (int ni = 0; ni < 4; ++ni)
        acc[mi][ni] = __builtin_amdgcn_mfma_f32_16x16x32_f16(af[mi], bf[ni], acc[mi][ni], 0, 0, 0);
    __builtin_amdgcn_s_setprio(0);
    b = (b == 2) ? 0 : b + 1;
  }
  {
    asm volatile("s_waitcnt vmcnt(0)" ::: "memory");
    __builtin_amdgcn_s_barrier();
    __builtin_amdgcn_sched_barrier(0);
    const char* bufp = SH + b * BUFB;
    f16x8 af[4], bf[4];
#pragma unroll
    for (int i = 0; i < 4; ++i) af[i] = *reinterpret_cast<const f16x8*>(bufp + abase + i * 1024);
#pragma unroll
    for (int i = 0; i < 4; ++i) bf[i] = *reinterpret_cast<const f16x8*>(bufp + bbase + i * 1024);
#pragma unroll
    for (int mi = 0; mi < 4; ++mi)
#pragma unroll
      for (int ni = 0; ni < 4; ++ni)
        acc[mi][ni] = __builtin_amdgcn_mfma_f32_16x16x32_f16(af[mi], bf[ni], acc[mi][ni], 0, 0, 0);
  }
  __syncthreads();

  // ---- EP2 epilogue via per-wave LDS transpose (64-col span) ----
  f16* tb = (f16*)SH + wid * 1088;  // 16x68 f16 per wave
  const int er = (lane >> 4) * 4;
  const int ec = lane & 15;
  const int rr = lane >> 3;        // 0..7
  const int cc = (lane & 7) * 8;   // 0..56
  const int colbase = bn + wc * 64;

#pragma unroll
  for (int mi = 0; mi < 4; ++mi) {
#pragma unroll
    for (int ni = 0; ni < 4; ++ni)
#pragma unroll
      for (int j = 0; j < 4; ++j)
        tb[(er + j) * 68 + ni * 16 + ec] = (f16)acc[mi][ni][j];
#pragma unroll
    for (int it = 0; it < 2; ++it) {
      const int row = rr + it * 8;
      const int gm = bm + wr * 64 + mi * 16 + row;
      const int gn = colbase + cc;
      f16x8 v = *reinterpret_cast<const f16x8*>(tb + row * 68 + cc);
      const size_t idx = (size_t)gm * 2048 + gn;
      float4 b0 = *reinterpret_cast<const float4*>(ep.bt2 + gn);
      float4 b1 = *reinterpret_cast<const float4*>(ep.bt2 + gn + 4);
      f16x8 df = *reinterpret_cast<const f16x8*>(ep.diff + idx);
      f16x8 hbv = *reinterpret_cast<const f16x8*>(ep.hb16 + idx);
      float bb[8] = {b0.x, b0.y, b0.z, b0.w, b1.x, b1.y, b1.z, b1.w};
      float on[8];
#pragma unroll
      for (int k = 0; k < 8; ++k) {
        float u = (float)v[k] + bb[k];
        float tau = softplus_fast(u) + TAU_MIN_F;
        on[k] = (float)hbv[k] + ep.coef * ((float)df[k] * rcp_fast(tau));
      }
      if (ep.out_f) {
        float4 o0 = {on[0], on[1], on[2], on[3]};
        float4 o1 = {on[4], on[5], on[6], on[7]};
        *reinterpret_cast<float4*>(ep.out_f + idx) = o0;
        *reinterpret_cast<float4*>(ep.out_f + idx + 4) = o1;
      } else {
        f16x8 o16;
#pragma unroll
        for (int k = 0; k < 8; ++k) o16[k] = (f16)on[k];
        *reinterpret_cast<f16x8*>(ep.out_h + idx) = o16;
      }
    }
  }
}

// ---------------- launch ----------------
extern "C" void kernel_launch(void* const* d_in, const int* in_sizes, int n_in,
                              void* d_out, int out_size, void* d_ws, size_t ws_size,
                              hipStream_t stream) {
  const float* x   = (const float*)d_in[0];
  const float* h   = (const float*)d_in[1];
  const float* Wih = (const float*)d_in[2];
  const float* bih = (const float*)d_in[3];
  const float* Whh = (const float*)d_in[4];
  const float* bhh = (const float*)d_in[5];
  const float* Wt1 = (const float*)d_in[6];
  const float* bt1 = (const float*)d_in[7];
  const float* Wt2 = (const float*)d_in[8];
  const float* bt2 = (const float*)d_in[9];
  float* hout = (float*)d_out;

  char* p = (char*)d_ws;
  auto alloc = [&](size_t bytes) {
    char* r = p;
    p += (bytes + 255) & ~(size_t)255;
    return r;
  };
  f16* xb    = (f16*)alloc((size_t)4096 * 1024 * 2);
  f16* Wpre  = (f16*)alloc((size_t)4096 * 1024 * 2);
  f16* Wab   = (f16*)alloc((size_t)4096 * 2048 * 2);
  f16* Wt2b  = (f16*)alloc((size_t)2048 * 2048 * 2);
  f16* hb    = (f16*)alloc((size_t)4096 * 2048 * 2);
  f16* hmb   = (f16*)alloc((size_t)4096 * 2048 * 2);
  f16* t1b   = (f16*)alloc((size_t)4096 * 2048 * 2);
  f16* pre16 = (f16*)alloc((size_t)4096 * 4096 * 2);
  f16* dif16 = (f16*)alloc((size_t)4096 * 2048 * 2);
  float* biasp = (float*)alloc(4096 * 4);

  prep_all<<<2048, 256, 0, stream>>>(x, h, Wih, Whh, Wt1, Wt2, bih, bhh, bt1,
                                     xb, hb, Wpre, Wab, Wt2b, biasp);

  // pre16 = f16(x @ [W_ih;W_t1x]^T + bias_pre)   (M=4096, N=4096, K=1024)
  {
    EpArgs e{};
    e.biasf = biasp;
    e.out_h = pre16;
    gemmT<0><<<dim3(16, 16), 512, 0, stream>>>(xb, Wpre, 4096, 1024, e);
  }

  const float dt = 1.0f / 3.0f;
  for (int s = 0; s < 3; ++s) {
    // k1 at h: EP1 then EP2 (h_mid = h + 0.5*dt*k1)
    {
      EpArgs e{};
      e.pre16 = pre16; e.h16 = hb; e.out_d = dif16; e.out_h = t1b;
      gemmT<1><<<dim3(16, 16), 512, 0, stream>>>(hb, Wab, 4096, 2048, e);
    }
    {
      EpArgs e{};
      e.bt2 = bt2; e.diff = dif16; e.hb16 = hb;
      e.coef = 0.5f * dt; e.out_f = nullptr; e.out_h = hmb;
      gemmC<<<dim3(32, 8), 512, 0, stream>>>(t1b, Wt2b, 2048, e);
    }
    // k2 at h_mid: EP1 then EP2 (h = h + dt*k2; in-place hb update safe per-lane)
    {
      EpArgs e{};
      e.pre16 = pre16; e.h16 = hmb; e.out_d = dif16; e.out_h = t1b;
      gemmT<1><<<dim3(16, 16), 512, 0, stream>>>(hmb, Wab, 4096, 2048, e);
    }
    {
      EpArgs e{};
      e.bt2 = bt2; e.diff = dif16; e.hb16 = hb;
      e.coef = dt; e.out_f = (s == 2) ? hout : nullptr; e.out_h = hb;
      gemmC<<<dim3(32, 8), 512, 0, stream>>>(t1b, Wt2b, 2048, e);
    }
  }
}